// Round 6
// baseline (55.139 us; speedup 1.0000x reference)
//
#include <hip/hip_runtime.h>
#include <hip/hip_bf16.h>

// Masked SDPA, B=16, NQ=NKV=2048, D=64, f32 in/out, bf16 MFMA compute.
// R6: (1) K+V double-buffered LDS with counted s_waitcnt vmcnt(4) + raw
// s_barrier (T3/T4 minimal form) -- stage latency hidden under compute, no
// vmcnt(0) drain in the loop; (2) P transpose done fully in registers via
// 16 shuffles (packed bf16 pairs) -- no P-LDS, no lgkmcnt(0) drain, 16 KB
// LDS freed for the double buffer. Prep pass (R5) unchanged: K/V -> bf16
// tile-swizzled / transposed LDS-image layouts in d_ws, once per element.

typedef __attribute__((ext_vector_type(8))) short short8;
typedef __attribute__((ext_vector_type(4))) short short4v;
typedef __attribute__((ext_vector_type(4))) float float4v;

#define BATCH 16
#define NQ 2048
#define NKV 2048
#define DH 64
#define KVB 64
#define NTILES (NKV / KVB)          // 32
#define TILE_ELEMS (KVB * DH)       // 4096 bf16 elems = 8 KB
#define NEG_INF -1e20f
// (1/sqrt(64)) * log2(e): softmax in base 2
#define SCALE_LOG2 0.180336880111120f

__device__ __forceinline__ short f2bf(float x) {
    union { float f; unsigned u; } v; v.f = x;
    unsigned r = (v.u + 0x7fffu + ((v.u >> 16) & 1u)) >> 16;
    return (short)r;
}

__device__ __forceinline__ short8 cvt8(float4v a, float4v b) {
    short8 r;
    r[0] = f2bf(a[0]); r[1] = f2bf(a[1]); r[2] = f2bf(a[2]); r[3] = f2bf(a[3]);
    r[4] = f2bf(b[0]); r[5] = f2bf(b[1]); r[6] = f2bf(b[2]); r[7] = f2bf(b[3]);
    return r;
}

// async global->LDS, 16B per lane (LDS dest: wave-uniform base + lane*16)
__device__ __forceinline__ void gll16(const short* g, short* l) {
    __builtin_amdgcn_global_load_lds(
        (const __attribute__((address_space(1))) unsigned int*)g,
        (__attribute__((address_space(3))) unsigned int*)l, 16, 0, 0);
}

// ---------------- prep: f32 -> bf16, LDS-image layouts in ws ----------------
__global__ __launch_bounds__(256) void prep_kernel(
    const float* __restrict__ K, const float* __restrict__ V,
    const int* __restrict__ valid_lens,
    short* __restrict__ Kws, short* __restrict__ Vws)
{
    const int b    = blockIdx.x >> 5;
    const int tile = blockIdx.x & 31;
    const int vlen = valid_lens[b];
    const int nkv  = (vlen == 0) ? NKV : vlen;
    if (tile * KVB >= nkv) return;          // never read by attn

    const int tid = threadIdx.x;
    const size_t gbase = ((size_t)b * NKV + (size_t)tile * KVB) * DH;
    short* kt = Kws + (((size_t)b * NTILES + tile) * TILE_ELEMS);
    short* vt = Vws + (((size_t)b * NTILES + tile) * TILE_ELEMS);

    {   // K: row-major [kv][d], col XOR-swizzled by (row&7)<<3
        const int row = tid >> 2;
        const int col = (tid & 3) << 4;
        const float* p = K + gbase + (size_t)row * DH + col;
        float4v a0 = *reinterpret_cast<const float4v*>(p);
        float4v a1 = *reinterpret_cast<const float4v*>(p + 4);
        float4v a2 = *reinterpret_cast<const float4v*>(p + 8);
        float4v a3 = *reinterpret_cast<const float4v*>(p + 12);
        const int sw = (row & 7) << 3;
        *reinterpret_cast<short8*>(&kt[row * DH + (col ^ sw)])       = cvt8(a0, a1);
        *reinterpret_cast<short8*>(&kt[row * DH + ((col + 8) ^ sw)]) = cvt8(a2, a3);
    }
    {   // V: transposed [d][kv], kv XOR-swizzled by (d&7)<<3
        const int kv = (tid >> 4) << 2;
        const int d  = (tid & 15) << 2;
        const float* p = V + gbase + (size_t)kv * DH + d;
        float4v r0 = *reinterpret_cast<const float4v*>(p);
        float4v r1 = *reinterpret_cast<const float4v*>(p + DH);
        float4v r2 = *reinterpret_cast<const float4v*>(p + 2 * DH);
        float4v r3 = *reinterpret_cast<const float4v*>(p + 3 * DH);
#pragma unroll
        for (int k = 0; k < 4; ++k) {
            const int dd = d + k;
            short4v w;
            w[0] = f2bf(r0[k]); w[1] = f2bf(r1[k]);
            w[2] = f2bf(r2[k]); w[3] = f2bf(r3[k]);
            *reinterpret_cast<short4v*>(
                &vt[dd * KVB + (kv ^ ((dd & 7) << 3))]) = w;
        }
    }
}

// ---------------- attn: 8 waves = 4 q-subtiles x 2 KV halves ----------------
__global__ __launch_bounds__(512) void attn_fwd_kernel(
    const float* __restrict__ Q,
    const short* __restrict__ Kws,
    const short* __restrict__ Vws,
    const int* __restrict__ valid_lens,
    float* __restrict__ O)
{
    __shared__ __align__(16) short k_lds[2][2][TILE_ELEMS];  // [buf][half]
    __shared__ __align__(16) short v_lds[2][2][TILE_ELEMS];  // [buf][half]

    const int tid  = threadIdx.x;
    const int wave = tid >> 6;
    const int lane = tid & 63;
    const int l15  = lane & 15;
    const int l4   = lane >> 4;
    const int h    = wave >> 2;            // KV half
    const int qsub = wave & 3;             // q sub-tile
    const int tb   = (lane & 48) | (l4 << 2);

    const int b  = blockIdx.x & 15;
    const int qt = blockIdx.x >> 4;        // 0..31
    const int qbase = qt * 64 + qsub * 16;

    const int vlen  = valid_lens[b];
    const int nkv   = (vlen == 0) ? NKV : vlen;
    const int tiles = (nkv + KVB - 1) / KVB;
    const int nh = (tiles + 1 - h) >> 1;   // my half's tile count (interleaved)
    const int n0 = (tiles + 1) >> 1;       // loop bound (max over halves)

    // Q B-fragment, scale pre-folded: lane col q=l15, k d = h2*32 + l4*8 + j
    const float* Qb = Q + ((size_t)b * NQ + qbase) * DH;
    short8 qfrag[2];
#pragma unroll
    for (int h2 = 0; h2 < 2; ++h2) {
        const float* p = Qb + (size_t)l15 * DH + h2 * 32 + l4 * 8;
        float4v a = *reinterpret_cast<const float4v*>(p);
        float4v c = *reinterpret_cast<const float4v*>(p + 4);
#pragma unroll
        for (int j = 0; j < 4; ++j) { a[j] *= SCALE_LOG2; c[j] *= SCALE_LOG2; }
        qfrag[h2] = cvt8(a, c);
    }

    const short* Kb = Kws + ((size_t)b * NTILES) * TILE_ELEMS;
    const short* Vb = Vws + ((size_t)b * NTILES) * TILE_ELEMS;
    const int soff = qsub * 512 + lane * 8;  // lane0 value = wave-uniform base

    auto stage = [&](int buf, int tile) {
        const short* kp = Kb + (size_t)tile * TILE_ELEMS + soff;
        const short* vp = Vb + (size_t)tile * TILE_ELEMS + soff;
        gll16(kp,        &k_lds[buf][h][soff]);
        gll16(kp + 2048, &k_lds[buf][h][soff + 2048]);
        gll16(vp,        &v_lds[buf][h][soff]);
        gll16(vp + 2048, &v_lds[buf][h][soff + 2048]);
    };

    float4v acc_o[4];
#pragma unroll
    for (int t = 0; t < 4; ++t) acc_o[t] = float4v{0.f, 0.f, 0.f, 0.f};
    float m = -INFINITY, lsum = 0.f;

    if (nh > 0) stage(0, h);               // first tile of my half (0 or 1)

    const int rsw  = (l15 & 7) << 3;       // read-side swizzle
    const int srcA = l15 + ((lane & 16) << 1);  // l15 + 32*(l4&1)
    const int srcB = srcA + 16;
    const bool hi  = (lane & 32) != 0;     // l4 >= 2

    for (int it = 0; it < n0; ++it) {
        const int cur = it & 1;
        // T3/T4: prefetch next tile into buf^1; counted wait (never 0 while
        // prefetching) lets next-tile loads stay in flight across the barrier.
        if (it + 1 < nh) {
            stage(cur ^ 1, 2 * (it + 1) + h);
            asm volatile("s_waitcnt vmcnt(4)" ::: "memory");
        } else {
            asm volatile("s_waitcnt vmcnt(0)" ::: "memory");
        }
        __builtin_amdgcn_s_barrier();      // all waves' tile-it loads visible
        asm volatile("" ::: "memory");

        if (it < nh) {
            const int tile = 2 * it + h;
            const short* kds = k_lds[cur][h];
            const short* vds = v_lds[cur][h];

            // ---- S^T = K Q^T (scale in Q): lane owns q=l15, kv=s*16+l4*4+r
            float4v accs[4];
#pragma unroll
            for (int s = 0; s < 4; ++s) accs[s] = float4v{0.f, 0.f, 0.f, 0.f};
            __builtin_amdgcn_s_setprio(1);
#pragma unroll
            for (int s = 0; s < 4; ++s) {
                const short* kb2 = &kds[(s * 16 + l15) * DH];
#pragma unroll
                for (int h2 = 0; h2 < 2; ++h2) {
                    short8 kf = *reinterpret_cast<const short8*>(
                        &kb2[(h2 * 32 + l4 * 8) ^ rsw]);
                    accs[s] = __builtin_amdgcn_mfma_f32_16x16x32_bf16(
                        kf, qfrag[h2], accs[s], 0, 0, 0);
                }
            }
            __builtin_amdgcn_s_setprio(0);

            // ---- mask (already log2 units) ----
            const int vlim = vlen - (tile * KVB + l4 * 4);
            float sv[4][4];
#pragma unroll
            for (int s = 0; s < 4; ++s)
#pragma unroll
                for (int r = 0; r < 4; ++r)
                    sv[s][r] = (s * 16 + r) < vlim ? accs[s][r] : NEG_INF;

            // ---- tile max: 15 in-lane + 2 shuffles ----
            float x = sv[0][0];
#pragma unroll
            for (int s = 0; s < 4; ++s)
#pragma unroll
                for (int r = 0; r < 4; ++r) x = fmaxf(x, sv[s][r]);
            x = fmaxf(x, __shfl_xor(x, 16, 64));
            x = fmaxf(x, __shfl_xor(x, 32, 64));

            // ---- T13 defer-max ----
            float mn = m;
            if (!__all(x <= m + 8.f)) {
                mn = fmaxf(m, x);
                const float alpha = exp2f(m - mn);   // m=-inf first -> 0
                m = mn;
                lsum *= alpha;
                float ar[4];
#pragma unroll
                for (int r = 0; r < 4; ++r) ar[r] = __shfl(alpha, tb + r, 64);
#pragma unroll
                for (int t = 0; t < 4; ++t)
#pragma unroll
                    for (int r = 0; r < 4; ++r) acc_o[t][r] *= ar[r];
            }

            // ---- P = exp2(sv - mn), in-lane sum + 2 shuffles ----
            float rsum = 0.f;
#pragma unroll
            for (int s = 0; s < 4; ++s)
#pragma unroll
                for (int r = 0; r < 4; ++r) {
                    const float p = exp2f(sv[s][r] - mn);
                    sv[s][r] = p;
                    rsum += p;
                }
            rsum += __shfl_xor(rsum, 16, 64);
            rsum += __shfl_xor(rsum, 32, 64);
            lsum += rsum;

            // ---- P -> bf16, in-register transpose to A-fragments ----
            // lane holds P[q=l15][kv=s*16+l4*4+r]; fragment needs
            // kv=ks*32+l4*8+j. src lanes: l15+16*((l4&1)*2+{0,1}),
            // s_sel=2ks+(l4>>1), j=r(+4).
            unsigned pp[4][2];
#pragma unroll
            for (int s = 0; s < 4; ++s) {
                pp[s][0] = ((unsigned)(unsigned short)f2bf(sv[s][1]) << 16) |
                           (unsigned short)f2bf(sv[s][0]);
                pp[s][1] = ((unsigned)(unsigned short)f2bf(sv[s][3]) << 16) |
                           (unsigned short)f2bf(sv[s][2]);
            }
            short8 pf[2];
#pragma unroll
            for (int ks = 0; ks < 2; ++ks) {
                union { unsigned u[4]; short8 s8; } t_;
#pragma unroll
                for (int k = 0; k < 2; ++k) {
                    const unsigned aLo = __shfl((int)pp[2 * ks][k],     srcA, 64);
                    const unsigned aHi = __shfl((int)pp[2 * ks + 1][k], srcA, 64);
                    const unsigned bLo = __shfl((int)pp[2 * ks][k],     srcB, 64);
                    const unsigned bHi = __shfl((int)pp[2 * ks + 1][k], srcB, 64);
                    t_.u[k]     = hi ? aHi : aLo;
                    t_.u[2 + k] = hi ? bHi : bLo;
                }
                pf[ks] = t_.s8;
            }

            // ---- O += P V ----
            __builtin_amdgcn_s_setprio(1);
#pragma unroll
            for (int t = 0; t < 4; ++t) {
                const short* vb2 = &vds[(t * 16 + l15) * KVB];
#pragma unroll
                for (int ks = 0; ks < 2; ++ks) {
                    short8 vf = *reinterpret_cast<const short8*>(
                        &vb2[(ks * 32 + l4 * 8) ^ rsw]);
                    acc_o[t] = __builtin_amdgcn_mfma_f32_16x16x32_bf16(
                        pf[ks], vf, acc_o[t], 0, 0, 0);
                }
            }
            __builtin_amdgcn_s_setprio(0);
        }

        asm volatile("" ::: "memory");
        __builtin_amdgcn_s_barrier();      // buf cur free for overwrite at it+2
    }

    // ---- merge the two KV halves; reuse k_lds (f32) / v_lds (ml) ----
    float*  mrg = reinterpret_cast<float*>(k_lds);
    float2* mlb = reinterpret_cast<float2*>(v_lds);
    __syncthreads();
    if (h == 1) {
#pragma unroll
        for (int t = 0; t < 4; ++t)
            *reinterpret_cast<float4v*>(
                &mrg[qsub * 1024 + t * 256 + lane * 4]) = acc_o[t];
        if (l4 == 0) mlb[qsub * 16 + l15] = float2{m, lsum};
    }
    __syncthreads();
    if (h == 0) {
        const float2 o1 = mlb[qsub * 16 + l15];
        const float m1 = o1.x, l1 = o1.y;
        const float M  = (l1 > 0.f) ? fmaxf(m, m1) : m;
        const float w0 = exp2f(m - M);
        const float w1 = (l1 > 0.f) ? exp2f(m1 - M) : 0.f;
        const float L  = lsum * w0 + l1 * w1;
        const float a0 = w0 / L, a1 = w1 / L;
        float a0r[4], a1r[4];
#pragma unroll
        for (int r = 0; r < 4; ++r) {
            a0r[r] = __shfl(a0, tb + r, 64);
            a1r[r] = __shfl(a1, tb + r, 64);
        }
        float* Ob = O + ((size_t)b * NQ + qbase) * DH;
#pragma unroll
        for (int t = 0; t < 4; ++t) {
            float4v oh = *reinterpret_cast<const float4v*>(
                &mrg[qsub * 1024 + t * 256 + lane * 4]);
#pragma unroll
            for (int r = 0; r < 4; ++r)
                Ob[(size_t)(l4 * 4 + r) * DH + t * 16 + l15] =
                    acc_o[t][r] * a0r[r] + oh[r] * a1r[r];
        }
    }
}

extern "C" void kernel_launch(void* const* d_in, const int* in_sizes, int n_in,
                              void* d_out, int out_size, void* d_ws, size_t ws_size,
                              hipStream_t stream) {
    const float* Q = (const float*)d_in[0];
    const float* K = (const float*)d_in[1];
    const float* V = (const float*)d_in[2];
    const int* vl  = (const int*)d_in[3];
    float* Out     = (float*)d_out;

    short* Kws = (short*)d_ws;
    short* Vws = Kws + (size_t)BATCH * NTILES * TILE_ELEMS;

    prep_kernel<<<dim3(BATCH * NTILES), dim3(256), 0, stream>>>(K, V, vl, Kws, Vws);
    attn_fwd_kernel<<<dim3(512), dim3(512), 0, stream>>>(Q, Kws, Vws, vl, Out);
}

// Round 7
// 46.373 us; speedup vs baseline: 1.1890x; 1.1890x over previous
//
#include <hip/hip_runtime.h>
#include <hip/hip_bf16.h>

// Masked SDPA, B=16, NQ=NKV=2048, D=64, f32 in/out, bf16 MFMA compute.
// R7 = R5 + two fixes:
//  (1) counted-vmcnt K/V double buffer (stage early -> vmcnt(4) -> barrier ->
//      compute -> barrier); P transpose back to per-wave P-LDS (R6's shuffle
//      transpose doubled LDS conflicts and regressed).
//  (2) CU batch de-pairing: blocks i and i+256 land on the same CU; the old
//      b=blockIdx&15 gave both the SAME batch (2x work on long-vlen CUs,
//      idle short-vlen CUs). New bijective map pairs batches (b, b+1).
// Prep pass unchanged: K/V -> bf16 tile-swizzled / transposed LDS-image
// layouts in d_ws, conversion paid once per element.

typedef __attribute__((ext_vector_type(8))) short short8;
typedef __attribute__((ext_vector_type(4))) short short4v;
typedef __attribute__((ext_vector_type(4))) float float4v;

#define BATCH 16
#define NQ 2048
#define NKV 2048
#define DH 64
#define KVB 64
#define NTILES (NKV / KVB)          // 32
#define TILE_ELEMS (KVB * DH)       // 4096 bf16 elems = 8 KB
#define NEG_INF -1e20f
// (1/sqrt(64)) * log2(e): softmax in base 2
#define SCALE_LOG2 0.180336880111120f

__device__ __forceinline__ short f2bf(float x) {
    union { float f; unsigned u; } v; v.f = x;
    unsigned r = (v.u + 0x7fffu + ((v.u >> 16) & 1u)) >> 16;
    return (short)r;
}

__device__ __forceinline__ short8 cvt8(float4v a, float4v b) {
    short8 r;
    r[0] = f2bf(a[0]); r[1] = f2bf(a[1]); r[2] = f2bf(a[2]); r[3] = f2bf(a[3]);
    r[4] = f2bf(b[0]); r[5] = f2bf(b[1]); r[6] = f2bf(b[2]); r[7] = f2bf(b[3]);
    return r;
}

// async global->LDS, 16B per lane (LDS dest: wave-uniform base + lane*16)
__device__ __forceinline__ void gll16(const short* g, short* l) {
    __builtin_amdgcn_global_load_lds(
        (const __attribute__((address_space(1))) unsigned int*)g,
        (__attribute__((address_space(3))) unsigned int*)l, 16, 0, 0);
}

// ---------------- prep: f32 -> bf16, LDS-image layouts in ws ----------------
__global__ __launch_bounds__(256) void prep_kernel(
    const float* __restrict__ K, const float* __restrict__ V,
    const int* __restrict__ valid_lens,
    short* __restrict__ Kws, short* __restrict__ Vws)
{
    const int b    = blockIdx.x >> 5;
    const int tile = blockIdx.x & 31;
    const int vlen = valid_lens[b];
    const int nkv  = (vlen == 0) ? NKV : vlen;
    if (tile * KVB >= nkv) return;          // never read by attn

    const int tid = threadIdx.x;
    const size_t gbase = ((size_t)b * NKV + (size_t)tile * KVB) * DH;
    short* kt = Kws + (((size_t)b * NTILES + tile) * TILE_ELEMS);
    short* vt = Vws + (((size_t)b * NTILES + tile) * TILE_ELEMS);

    {   // K: row-major [kv][d], col XOR-swizzled by (row&7)<<3
        const int row = tid >> 2;
        const int col = (tid & 3) << 4;
        const float* p = K + gbase + (size_t)row * DH + col;
        float4v a0 = *reinterpret_cast<const float4v*>(p);
        float4v a1 = *reinterpret_cast<const float4v*>(p + 4);
        float4v a2 = *reinterpret_cast<const float4v*>(p + 8);
        float4v a3 = *reinterpret_cast<const float4v*>(p + 12);
        const int sw = (row & 7) << 3;
        *reinterpret_cast<short8*>(&kt[row * DH + (col ^ sw)])       = cvt8(a0, a1);
        *reinterpret_cast<short8*>(&kt[row * DH + ((col + 8) ^ sw)]) = cvt8(a2, a3);
    }
    {   // V: transposed [d][kv], kv XOR-swizzled by (d&7)<<3
        const int kv = (tid >> 4) << 2;
        const int d  = (tid & 15) << 2;
        const float* p = V + gbase + (size_t)kv * DH + d;
        float4v r0 = *reinterpret_cast<const float4v*>(p);
        float4v r1 = *reinterpret_cast<const float4v*>(p + DH);
        float4v r2 = *reinterpret_cast<const float4v*>(p + 2 * DH);
        float4v r3 = *reinterpret_cast<const float4v*>(p + 3 * DH);
#pragma unroll
        for (int k = 0; k < 4; ++k) {
            const int dd = d + k;
            short4v w;
            w[0] = f2bf(r0[k]); w[1] = f2bf(r1[k]);
            w[2] = f2bf(r2[k]); w[3] = f2bf(r3[k]);
            *reinterpret_cast<short4v*>(
                &vt[dd * KVB + (kv ^ ((dd & 7) << 3))]) = w;
        }
    }
}

// ---------------- attn: 8 waves = 4 q-subtiles x 2 KV halves ----------------
__global__ __launch_bounds__(512) void attn_fwd_kernel(
    const float* __restrict__ Q,
    const short* __restrict__ Kws,
    const short* __restrict__ Vws,
    const int* __restrict__ valid_lens,
    float* __restrict__ O)
{
    __shared__ __align__(16) short k_lds[2][2][TILE_ELEMS];  // [buf][half]
    __shared__ __align__(16) short v_lds[2][2][TILE_ELEMS];  // [buf][half]
    __shared__ __align__(16) short p_lds[8][16 * KVB];       // per-wave P

    const int tid  = threadIdx.x;
    const int wave = tid >> 6;
    const int lane = tid & 63;
    const int l15  = lane & 15;
    const int l4   = lane >> 4;
    const int h    = wave >> 2;            // KV half
    const int qsub = wave & 3;             // q sub-tile
    const int tb   = (lane & 48) | (l4 << 2);

    // CU de-pairing map: blocks i and i+256 share a CU; give them batches
    // (b, b+1). Bijective over (b, qt).
    const int hi = blockIdx.x >> 8;        // 0 or 1
    const int lo = blockIdx.x & 255;
    const int qt = hi * 16 + (lo >> 4);    // 0..31
    const int b  = (lo + hi) & 15;
    const int qbase = qt * 64 + qsub * 16;

    const int vlen  = valid_lens[b];
    const int nkv   = (vlen == 0) ? NKV : vlen;
    const int tiles = (nkv + KVB - 1) / KVB;
    const int nh = (tiles + 1 - h) >> 1;   // my half's tile count (interleaved)
    const int n0 = (tiles + 1) >> 1;       // loop bound (max over halves)

    // Q B-fragment, scale pre-folded: lane col q=l15, k d = h2*32 + l4*8 + j
    const float* Qb = Q + ((size_t)b * NQ + qbase) * DH;
    short8 qfrag[2];
#pragma unroll
    for (int h2 = 0; h2 < 2; ++h2) {
        const float* p = Qb + (size_t)l15 * DH + h2 * 32 + l4 * 8;
        float4v a = *reinterpret_cast<const float4v*>(p);
        float4v c = *reinterpret_cast<const float4v*>(p + 4);
#pragma unroll
        for (int j = 0; j < 4; ++j) { a[j] *= SCALE_LOG2; c[j] *= SCALE_LOG2; }
        qfrag[h2] = cvt8(a, c);
    }

    const short* Kb = Kws + ((size_t)b * NTILES) * TILE_ELEMS;
    const short* Vb = Vws + ((size_t)b * NTILES) * TILE_ELEMS;
    const int soff = qsub * 512 + lane * 8;  // wave-uniform base + lane*16B

    auto stage = [&](int buf, int tile) {
        const short* kp = Kb + (size_t)tile * TILE_ELEMS + soff;
        const short* vp = Vb + (size_t)tile * TILE_ELEMS + soff;
        gll16(kp,        &k_lds[buf][h][soff]);
        gll16(kp + 2048, &k_lds[buf][h][soff + 2048]);
        gll16(vp,        &v_lds[buf][h][soff]);
        gll16(vp + 2048, &v_lds[buf][h][soff + 2048]);
    };

    float4v acc_o[4];
#pragma unroll
    for (int t = 0; t < 4; ++t) acc_o[t] = float4v{0.f, 0.f, 0.f, 0.f};
    float m = -INFINITY, lsum = 0.f;

    if (nh > 0) stage(0, h);               // first tile of my half (0 or 1)

    const int rsw = (l15 & 7) << 3;        // read-side swizzle

    for (int it = 0; it < n0; ++it) {
        const int cur = it & 1;
        // T3/T4: prefetch next tile into buf^1; counted wait keeps next-tile
        // loads in flight across the barrier (never drain to 0 mid-loop).
        if (it + 1 < nh) {
            stage(cur ^ 1, 2 * (it + 1) + h);
            asm volatile("s_waitcnt vmcnt(4)" ::: "memory");
        } else {
            asm volatile("s_waitcnt vmcnt(0)" ::: "memory");
        }
        __builtin_amdgcn_s_barrier();      // tile-it loads of all waves visible
        asm volatile("" ::: "memory");

        if (it < nh) {
            const int tile = 2 * it + h;
            const short* kds = k_lds[cur][h];
            const short* vds = v_lds[cur][h];

            // ---- S^T = K Q^T (scale in Q): lane owns q=l15, kv=s*16+l4*4+r
            float4v accs[4];
#pragma unroll
            for (int s = 0; s < 4; ++s) accs[s] = float4v{0.f, 0.f, 0.f, 0.f};
            __builtin_amdgcn_s_setprio(1);
#pragma unroll
            for (int s = 0; s < 4; ++s) {
                const short* kb2 = &kds[(s * 16 + l15) * DH];
#pragma unroll
                for (int h2 = 0; h2 < 2; ++h2) {
                    short8 kf = *reinterpret_cast<const short8*>(
                        &kb2[(h2 * 32 + l4 * 8) ^ rsw]);
                    accs[s] = __builtin_amdgcn_mfma_f32_16x16x32_bf16(
                        kf, qfrag[h2], accs[s], 0, 0, 0);
                }
            }
            __builtin_amdgcn_s_setprio(0);

            // ---- mask (already log2 units) ----
            const int vlim = vlen - (tile * KVB + l4 * 4);
            float sv[4][4];
#pragma unroll
            for (int s = 0; s < 4; ++s)
#pragma unroll
                for (int r = 0; r < 4; ++r)
                    sv[s][r] = (s * 16 + r) < vlim ? accs[s][r] : NEG_INF;

            // ---- tile max: 15 in-lane + 2 shuffles ----
            float x = sv[0][0];
#pragma unroll
            for (int s = 0; s < 4; ++s)
#pragma unroll
                for (int r = 0; r < 4; ++r) x = fmaxf(x, sv[s][r]);
            x = fmaxf(x, __shfl_xor(x, 16, 64));
            x = fmaxf(x, __shfl_xor(x, 32, 64));

            // ---- T13 defer-max ----
            float mn = m;
            if (!__all(x <= m + 8.f)) {
                mn = fmaxf(m, x);
                const float alpha = exp2f(m - mn);   // m=-inf first -> 0
                m = mn;
                lsum *= alpha;
                float ar[4];
#pragma unroll
                for (int r = 0; r < 4; ++r) ar[r] = __shfl(alpha, tb + r, 64);
#pragma unroll
                for (int t = 0; t < 4; ++t)
#pragma unroll
                    for (int r = 0; r < 4; ++r) acc_o[t][r] *= ar[r];
            }

            // ---- P = exp2(sv - mn), in-lane sum + 2 shuffles ----
            float rsum = 0.f;
#pragma unroll
            for (int s = 0; s < 4; ++s)
#pragma unroll
                for (int r = 0; r < 4; ++r) {
                    const float p = exp2f(sv[s][r] - mn);
                    sv[s][r] = p;
                    rsum += p;
                }
            rsum += __shfl_xor(rsum, 16, 64);
            rsum += __shfl_xor(rsum, 32, 64);
            lsum += rsum;

            // ---- P -> bf16 -> per-wave swizzled LDS (C/D -> A layout) ----
            short* pw = p_lds[wave];
#pragma unroll
            for (int s = 0; s < 4; ++s) {
                short4v w;
                w[0] = f2bf(sv[s][0]); w[1] = f2bf(sv[s][1]);
                w[2] = f2bf(sv[s][2]); w[3] = f2bf(sv[s][3]);
                *reinterpret_cast<short4v*>(
                    &pw[l15 * KVB + ((s * 16 + l4 * 4) ^ ((l15 & 7) << 3))]) = w;
            }
            asm volatile("s_waitcnt lgkmcnt(0)" ::: "memory");
            short8 pf[2];
#pragma unroll
            for (int ks = 0; ks < 2; ++ks)
                pf[ks] = *reinterpret_cast<const short8*>(
                    &pw[l15 * KVB + ((ks * 32 + l4 * 8) ^ rsw)]);

            // ---- O += P V ----
            __builtin_amdgcn_s_setprio(1);
#pragma unroll
            for (int t = 0; t < 4; ++t) {
                const short* vb2 = &vds[(t * 16 + l15) * KVB];
#pragma unroll
                for (int ks = 0; ks < 2; ++ks) {
                    short8 vf = *reinterpret_cast<const short8*>(
                        &vb2[(ks * 32 + l4 * 8) ^ rsw]);
                    acc_o[t] = __builtin_amdgcn_mfma_f32_16x16x32_bf16(
                        pf[ks], vf, acc_o[t], 0, 0, 0);
                }
            }
            __builtin_amdgcn_s_setprio(0);
        }

        asm volatile("" ::: "memory");
        __builtin_amdgcn_s_barrier();      // buf cur free for overwrite at it+2
    }

    // ---- merge the two KV halves; reuse k_lds (f32) / v_lds (ml) ----
    float*  mrg = reinterpret_cast<float*>(k_lds);
    float2* mlb = reinterpret_cast<float2*>(v_lds);
    __syncthreads();
    if (h == 1) {
#pragma unroll
        for (int t = 0; t < 4; ++t)
            *reinterpret_cast<float4v*>(
                &mrg[qsub * 1024 + t * 256 + lane * 4]) = acc_o[t];
        if (l4 == 0) mlb[qsub * 16 + l15] = float2{m, lsum};
    }
    __syncthreads();
    if (h == 0) {
        const float2 o1 = mlb[qsub * 16 + l15];
        const float m1 = o1.x, l1 = o1.y;
        const float M  = (l1 > 0.f) ? fmaxf(m, m1) : m;
        const float w0 = exp2f(m - M);
        const float w1 = (l1 > 0.f) ? exp2f(m1 - M) : 0.f;
        const float L  = lsum * w0 + l1 * w1;
        const float a0 = w0 / L, a1 = w1 / L;
        float a0r[4], a1r[4];
#pragma unroll
        for (int r = 0; r < 4; ++r) {
            a0r[r] = __shfl(a0, tb + r, 64);
            a1r[r] = __shfl(a1, tb + r, 64);
        }
        float* Ob = O + ((size_t)b * NQ + qbase) * DH;
#pragma unroll
        for (int t = 0; t < 4; ++t) {
            float4v oh = *reinterpret_cast<const float4v*>(
                &mrg[qsub * 1024 + t * 256 + lane * 4]);
#pragma unroll
            for (int r = 0; r < 4; ++r)
                Ob[(size_t)(l4 * 4 + r) * DH + t * 16 + l15] =
                    acc_o[t][r] * a0r[r] + oh[r] * a1r[r];
        }
    }
}

extern "C" void kernel_launch(void* const* d_in, const int* in_sizes, int n_in,
                              void* d_out, int out_size, void* d_ws, size_t ws_size,
                              hipStream_t stream) {
    const float* Q = (const float*)d_in[0];
    const float* K = (const float*)d_in[1];
    const float* V = (const float*)d_in[2];
    const int* vl  = (const int*)d_in[3];
    float* Out     = (float*)d_out;

    short* Kws = (short*)d_ws;
    short* Vws = Kws + (size_t)BATCH * NTILES * TILE_ELEMS;

    prep_kernel<<<dim3(BATCH * NTILES), dim3(256), 0, stream>>>(K, V, vl, Kws, Vws);
    attn_fwd_kernel<<<dim3(512), dim3(512), 0, stream>>>(Q, Kws, Vws, vl, Out);
}